// Round 3
// baseline (191.965 us; speedup 1.0000x reference)
//
#include <hip/hip_runtime.h>
#include <hip/hip_bf16.h>
#include <stdint.h>

#define B_DIM 32768
#define IN_DIM 512
#define OUT_DIM 512
#define PAD 72   // LDS row stride (elems) = 64+8: conflict-free for b128 r/w patterns

typedef __bf16 bf16;
typedef bf16 bf16x8 __attribute__((ext_vector_type(8)));
typedef float f32x4 __attribute__((ext_vector_type(4)));

// xi = trunc(v*2^sf); keep top-4 significant bits of |xi|; sign restored.
// fp32-bit equivalent: truncf then mask mantissa to 3 stored bits (+implicit = 4).
// Masked value's low 16 bits are 0 -> top half IS the exact bf16.
__device__ __forceinline__ uint32_t quant2(float a, float b, float scale) {
    uint32_t ua = __float_as_uint(truncf(a * scale)) & 0xFFF00000u;
    uint32_t ub = __float_as_uint(truncf(b * scale)) & 0xFFF00000u;
    return (ua >> 16) | (ub & 0xFFFF0000u);   // packed bf16 pair
}

__global__ void quant_kernel(const float* __restrict__ in, bf16* __restrict__ out,
                             int n4, const int* __restrict__ sf) {
    int i = blockIdx.x * blockDim.x + threadIdx.x;
    if (i >= n4) return;
    float scale = (float)(1 << *sf);
    float4 v = ((const float4*)in)[i];
    uint2 p;
    p.x = quant2(v.x, v.y, scale);
    p.y = quant2(v.z, v.w, scale);
    ((uint2*)out)[i] = p;
}

// Fused GEMM: C[m,n] = (sum_k q(x[m,k])*qw[n,k]) * 2^-(asf+wsf) + bias[n]
// Software-pipelined: tile k+1 global->regs overlaps compute(k); regs->LDS after barrier.
__global__ __launch_bounds__(256, 3)
void gemm_fused(const float* __restrict__ X, const bf16* __restrict__ QW,
                const float* __restrict__ bias, float* __restrict__ C,
                const int* __restrict__ wsf, const int* __restrict__ asf) {
    __shared__ bf16 As[128 * PAD];
    __shared__ bf16 Bs[128 * PAD];

    const int t    = threadIdx.x;
    const int w    = t >> 6;
    const int lane = t & 63;

    // XCD swizzle: same-M blocks adjacent on one XCD for L2 reuse of A.
    const int b    = blockIdx.x;
    const int xcd  = b & 7;
    const int slot = b >> 3;
    const int bm   = xcd * 32 + (slot >> 2);
    const int bn   = slot & 3;
    const int row0 = bm * 128;
    const int col0 = bn * 128;
    const int wm   = (w & 1) * 64;
    const int wn   = (w >> 1) * 64;

    const int ldr = t >> 3;          // 0..31
    const int ldc = (t & 7) * 8;     // 0,8,..,56

    const float* Xp = X  + (size_t)(row0 + ldr) * IN_DIM + ldc;
    const bf16*  Wp = QW + (size_t)(col0 + ldr) * IN_DIM + ldc;
    const float ascale = (float)(1 << *asf);

    f32x4 acc[4][4];
    #pragma unroll
    for (int mt = 0; mt < 4; ++mt)
        #pragma unroll
        for (int nt = 0; nt < 4; ++nt)
            acc[mt][nt] = 0.0f;

    float4 a0[4], a1[4];   // A prefetch regs (8 fp32/chunk)
    uint4  bv[4];          // B prefetch regs (8 bf16/chunk)

    auto stage = [&](int k0) {       // issue global loads for tile k0
        #pragma unroll
        for (int i = 0; i < 4; ++i) {
            const float* g = Xp + (size_t)i * 32 * IN_DIM + k0;
            a0[i] = ((const float4*)g)[0];
            a1[i] = ((const float4*)g)[1];
            bv[i] = *(const uint4*)(Wp + (size_t)i * 32 * IN_DIM + k0);
        }
    };
    auto commit = [&]() {            // quant + regs -> LDS (padded)
        #pragma unroll
        for (int i = 0; i < 4; ++i) {
            uint4 p;
            p.x = quant2(a0[i].x, a0[i].y, ascale);
            p.y = quant2(a0[i].z, a0[i].w, ascale);
            p.z = quant2(a1[i].x, a1[i].y, ascale);
            p.w = quant2(a1[i].z, a1[i].w, ascale);
            *(uint4*)(As + (i * 32 + ldr) * PAD + ldc) = p;
            *(uint4*)(Bs + (i * 32 + ldr) * PAD + ldc) = bv[i];
        }
    };
    auto compute = [&]() {
        #pragma unroll
        for (int ks = 0; ks < 2; ++ks) {
            const int kcol = ks * 32 + (lane >> 4) * 8;
            const int arow = wm + (lane & 15);
            const int brow = wn + (lane & 15);
            bf16x8 af[4], bfr[4];
            #pragma unroll
            for (int mt = 0; mt < 4; ++mt)
                af[mt] = *(const bf16x8*)(As + (arow + mt * 16) * PAD + kcol);
            #pragma unroll
            for (int nt = 0; nt < 4; ++nt)
                bfr[nt] = *(const bf16x8*)(Bs + (brow + nt * 16) * PAD + kcol);
            #pragma unroll
            for (int mt = 0; mt < 4; ++mt)
                #pragma unroll
                for (int nt = 0; nt < 4; ++nt)
                    acc[mt][nt] = __builtin_amdgcn_mfma_f32_16x16x32_bf16(af[mt], bfr[nt], acc[mt][nt], 0, 0, 0);
        }
    };

    // pipeline: stage(0) -> commit -> [stage(k+1); compute(k); sync; commit; sync] -> compute(last)
    stage(0);
    commit();
    __syncthreads();
    #pragma unroll
    for (int k0 = 64; k0 < IN_DIM; k0 += 64) {
        stage(k0);          // loads in flight during compute below
        compute();
        __syncthreads();    // all waves done reading LDS; prefetch landed
        commit();
        __syncthreads();    // LDS writes visible
    }
    compute();

    // epilogue: C/D layout col=lane&15, row=(lane>>4)*4+reg
    const float oscale = ldexpf(1.0f, -(*wsf + *asf));
    const int cl = lane & 15;
    const int rg = (lane >> 4) * 4;
    #pragma unroll
    for (int nt = 0; nt < 4; ++nt) {
        const int col = col0 + wn + nt * 16 + cl;
        const float bvl = bias[col];
        #pragma unroll
        for (int mt = 0; mt < 4; ++mt) {
            f32x4 a = acc[mt][nt];
            #pragma unroll
            for (int r = 0; r < 4; ++r) {
                const int row = row0 + wm + mt * 16 + rg + r;
                C[(size_t)row * OUT_DIM + col] = a[r] * oscale + bvl;
            }
        }
    }
}

extern "C" void kernel_launch(void* const* d_in, const int* in_sizes, int n_in,
                              void* d_out, int out_size, void* d_ws, size_t ws_size,
                              hipStream_t stream) {
    const float* x    = (const float*)d_in[0];
    const float* wgt  = (const float*)d_in[1];
    const float* bias = (const float*)d_in[2];
    const int*   wsf  = (const int*)d_in[3];
    const int*   asf  = (const int*)d_in[4];

    bf16* tw = (bf16*)d_ws;   // 512 KB quantized weight

    const int nw4 = OUT_DIM * IN_DIM / 4;
    quant_kernel<<<(nw4 + 255) / 256, 256, 0, stream>>>(wgt, tw, nw4, wsf);

    const int grid = (B_DIM / 128) * (OUT_DIM / 128); // 1024
    gemm_fused<<<grid, 256, 0, stream>>>(x, tw, bias, (float*)d_out, wsf, asf);
}